// Round 2
// baseline (532.870 us; speedup 1.0000x reference)
//
#include <hip/hip_runtime.h>
#include <cstdint>

typedef short bf16x8 __attribute__((ext_vector_type(8)));
typedef float f32x4  __attribute__((ext_vector_type(4)));

#define TOK    64         // tokens per block
#define PITCH  264        // ushorts/row (256 + 8 pad; 132 dw = 4 mod 32)
#define CROWS  32         // codes per chunk (per K-half)
#define MAXC   16

__device__ __forceinline__ unsigned short f2bf(float f) {
  unsigned u = __float_as_uint(f);
  return (unsigned short)((u + 0x7FFFu + ((u >> 16) & 1u)) >> 16);
}
__device__ __forceinline__ uint4 pack8(float4 a, float4 b) {
  uint4 u;
  u.x = (unsigned)f2bf(a.x) | ((unsigned)f2bf(a.y) << 16);
  u.y = (unsigned)f2bf(a.z) | ((unsigned)f2bf(a.w) << 16);
  u.z = (unsigned)f2bf(b.x) | ((unsigned)f2bf(b.y) << 16);
  u.w = (unsigned)f2bf(b.z) | ((unsigned)f2bf(b.w) << 16);
  return u;
}

// ---------------------------------------------------------------------------
// Prep: cb_bf = bf16(cb), ee = ||cb_k||^2. Block 0 zeroes global accumulators.
// ---------------------------------------------------------------------------
__global__ __launch_bounds__(256) void vq_prep(const float* __restrict__ cb,
                                               unsigned short* __restrict__ cb_bf,
                                               float* __restrict__ ee,
                                               float* __restrict__ acc2,
                                               int* __restrict__ done_ctr, int K) {
  if (blockIdx.x == 0 && threadIdx.x == 0) {
    acc2[0] = 0.f; acc2[1] = 0.f; *done_ctr = 0;
  }
  int wave = threadIdx.x >> 6, lane = threadIdx.x & 63;
  int k = blockIdx.x * 4 + wave;
  if (k >= K) return;
  float4 v = *reinterpret_cast<const float4*>(cb + (size_t)k * 256 + lane * 4);
  float s = v.x * v.x + v.y * v.y + v.z * v.z + v.w * v.w;
  #pragma unroll
  for (int off = 32; off; off >>= 1) s += __shfl_down(s, off, 64);
  ushort4 b;
  b.x = f2bf(v.x); b.y = f2bf(v.y); b.z = f2bf(v.z); b.w = f2bf(v.w);
  *reinterpret_cast<ushort4*>(cb_bf + (size_t)k * 256 + lane * 4) = b;
  if (lane == 0) ee[k] = s;
}

// ---------------------------------------------------------------------------
// Main: 256 thr (4 waves), TOK=64, grid 512. LDS ~38.7 KB -> 4 blocks/CU
// = 16 waves/CU = 4 waves/SIMD (2x the 76.8 KB/2-block R0 config).
// DO NOT use 512-thread blocks: both (512,4) and (512,2) trigger a compiler
// pathology (VGPR crushed to 64, ~40-reg spill, WRITE_SIZE 33->290 MB).
// Wave (kh = wv>>1, p = wv&1): tokens [32p,32p+32) as 2 A-sets in regs,
// K-half kh (512 codes = 16 chunks of 32). ee lives in GLOBAL (L1-resident
// 4 KB) to keep LDS under the 40960 B 4-block threshold.
// Screen gate = min(running amin, chunk min, global packed umin). Candidates
// stored packed (fp32dist&~1023 | idx); two-tier epilogue: unique in-margin
// candidate -> zero rescore dots; else exact fp32 rescore of in-margin set.
// ---------------------------------------------------------------------------
__global__ __launch_bounds__(256, 2) void vq_main(
    const float* __restrict__ z, const float* __restrict__ cb,
    const unsigned short* __restrict__ cb_bf, const float* __restrict__ ee,
    const float* __restrict__ mask,
    float* __restrict__ out_q, float* __restrict__ out_idx_f,
    float* __restrict__ out_loss, float* __restrict__ acc2,
    int* __restrict__ done_ctr, int nblocks, int K) {
  __shared__ __align__(16) unsigned short buf[64 * PITCH];   // 33792 B: z-stage, then 2x32-row chunk bufs
  __shared__ float znorm[TOK];
  __shared__ int   ccnt[TOK];
  __shared__ unsigned umin[TOK];                             // packed (dist22|idx10) running min
  __shared__ unsigned cand[TOK * MAXC];                      // 4 KB packed candidates
  __shared__ float red[8];
  __shared__ bool  last;

  const int t = threadIdx.x;
  const int n0 = blockIdx.x * TOK;
  const int wv = t >> 6, lane = t & 63;
  const int p = wv & 1, kh = wv >> 1;
  const int quad = lane >> 4, l15 = lane & 15;
  const int q16 = t & 15;

  if (t < TOK) { ccnt[t] = 0; umin[t] = 0x7F7FFC00u; }

  // ---- enmax partial (max ||c|| over all K, for epilogue threshold) ----
  float em = fmaxf(fmaxf(ee[t], ee[t + 256]), fmaxf(ee[t + 512], ee[t + 768]));
  #pragma unroll
  for (int off = 32; off; off >>= 1) em = fmaxf(em, __shfl_xor(em, off, 64));
  if (lane == 0) red[wv] = em;

  // ---- stage z -> bf16 into buf rows 0..63; ||z|| ----
  #pragma unroll
  for (int pass = 0; pass < 4; ++pass) {
    int row = pass * 16 + (t >> 4);
    const float* zr = z + (size_t)(n0 + row) * 256;
    float ssq = 0.f;
    #pragma unroll
    for (int j = 0; j < 2; ++j) {
      float4 a = *reinterpret_cast<const float4*>(zr + q16 * 8 + j * 128);
      float4 b = *reinterpret_cast<const float4*>(zr + q16 * 8 + j * 128 + 4);
      ssq += a.x*a.x + a.y*a.y + a.z*a.z + a.w*a.w
           + b.x*b.x + b.y*b.y + b.z*b.z + b.w*b.w;
      *reinterpret_cast<uint4*>(&buf[row * PITCH + q16 * 8 + j * 128]) = pack8(a, b);
    }
    #pragma unroll
    for (int off = 1; off < 16; off <<= 1) ssq += __shfl_xor(ssq, off, 64);
    if (q16 == 0) znorm[row] = sqrtf(ssq);
  }
  __syncthreads();  // S1: z staged, red[] written

  const float enmax = sqrtf(fmaxf(fmaxf(red[0], red[1]), fmaxf(red[2], red[3])));

  // ---- A fragments into registers ----
  bf16x8 afrag[2][8];
  float  znreg[2][4];
  #pragma unroll
  for (int s = 0; s < 2; ++s) {
    const unsigned short* za = &buf[(p * 32 + s * 16 + l15) * PITCH + quad * 8];
    #pragma unroll
    for (int kk = 0; kk < 8; ++kk)
      afrag[s][kk] = *reinterpret_cast<const bf16x8*>(za + kk * 32);
    #pragma unroll
    for (int r = 0; r < 4; ++r)
      znreg[s][r] = znorm[p * 32 + s * 16 + quad * 4 + r];
  }
  __syncthreads();  // S2: all A-loads done before chunk staging overwrites buf

  unsigned short* qbuf = &buf[kh * CROWS * PITCH];
  const unsigned short* cbh = cb_bf + (size_t)kh * 512 * 256;
  const int tq = t & 127;   // index within kh half-group (128 threads)

  float amin[2][4];
  #pragma unroll
  for (int s = 0; s < 2; ++s)
    #pragma unroll
    for (int r = 0; r < 4; ++r) amin[s][r] = 3.4e38f;

  // ---- chunk loop: 16 chunks x 32 codes per K-half ----
  for (int lc = 0; lc < 16; ++lc) {
    const int kbase = kh * 512 + lc * CROWS;
    // stage chunk: 32 rows x 512 B via 128 threads (8 x 16B each)
    #pragma unroll
    for (int g = 0; g < 2; ++g) {
      uint4 v[4];
      #pragma unroll
      for (int u = 0; u < 4; ++u) {
        int flat = (g * 4 + u) * 128 + tq;
        v[u] = *reinterpret_cast<const uint4*>(
            cbh + (size_t)(lc * CROWS + (flat >> 5)) * 256 + (flat & 31) * 8);
      }
      #pragma unroll
      for (int u = 0; u < 4; ++u) {
        int flat = (g * 4 + u) * 128 + tq;
        *reinterpret_cast<uint4*>(&qbuf[(flat >> 5) * PITCH + (flat & 31) * 8]) = v[u];
      }
    }
    __syncthreads();

    f32x4 acc[2][2];
    #pragma unroll
    for (int s = 0; s < 2; ++s)
      #pragma unroll
      for (int ct = 0; ct < 2; ++ct) acc[s][ct] = (f32x4){0.f, 0.f, 0.f, 0.f};
    __builtin_amdgcn_s_setprio(1);
    #pragma unroll
    for (int kk = 0; kk < 8; ++kk) {
      bf16x8 b0 = *reinterpret_cast<const bf16x8*>(&qbuf[(l15)      * PITCH + quad * 8 + kk * 32]);
      bf16x8 b1 = *reinterpret_cast<const bf16x8*>(&qbuf[(16 + l15) * PITCH + quad * 8 + kk * 32]);
      acc[0][0] = __builtin_amdgcn_mfma_f32_16x16x32_bf16(afrag[0][kk], b0, acc[0][0], 0, 0, 0);
      acc[1][0] = __builtin_amdgcn_mfma_f32_16x16x32_bf16(afrag[1][kk], b0, acc[1][0], 0, 0, 0);
      acc[0][1] = __builtin_amdgcn_mfma_f32_16x16x32_bf16(afrag[0][kk], b1, acc[0][1], 0, 0, 0);
      acc[1][1] = __builtin_amdgcn_mfma_f32_16x16x32_bf16(afrag[1][kk], b1, acc[1][1], 0, 0, 0);
    }
    __builtin_amdgcn_s_setprio(0);

    // screen: margin >= 2*eps(bf16) + 0.13 (22-bit packed-dist truncation)
    float e0 = ee[kbase + l15], e1 = ee[kbase + 16 + l15];
    float en0 = sqrtf(e0), en1 = sqrtf(e1);
    #pragma unroll
    for (int s = 0; s < 2; ++s) {
      #pragma unroll
      for (int r = 0; r < 4; ++r) {
        float d0 = e0 - 2.f * acc[s][0][r];
        float d1 = e1 - 2.f * acc[s][1][r];
        float w = fminf(d0, d1);
        #pragma unroll
        for (int off = 1; off < 16; off <<= 1) w = fminf(w, __shfl_xor(w, off, 64));
        int tok = p * 32 + s * 16 + quad * 4 + r;
        float gq = __uint_as_float(umin[tok] & 0xFFFFFC00u);  // stale-read ok (conservative)
        float am = fminf(fminf(amin[s][r], w), gq);
        amin[s][r] = am;
        float zn = znreg[s][r];
        if (d0 <= am + 1.63f + 0.002f * zn * en0) {
          unsigned pu = (__float_as_uint(fmaxf(d0, 0.f)) & 0xFFFFFC00u) | (unsigned)(kbase + l15);
          atomicMin(&umin[tok], pu);
          int sl = atomicAdd(&ccnt[tok], 1);
          if (sl < MAXC) cand[tok * MAXC + sl] = pu;
        }
        if (d1 <= am + 1.63f + 0.002f * zn * en1) {
          unsigned pu = (__float_as_uint(fmaxf(d1, 0.f)) & 0xFFFFFC00u) | (unsigned)(kbase + 16 + l15);
          atomicMin(&umin[tok], pu);
          int sl = atomicAdd(&ccnt[tok], 1);
          if (sl < MAXC) cand[tok * MAXC + sl] = pu;
        }
      }
    }
    __syncthreads();  // all reads of qbuf done before next stage
  }

  // ---- two-tier epilogue: 4 waves x 16 tokens ----
  float lsum = 0.f, msum = 0.f;
  for (int it = 0; it < 16; ++it) {
    int tok = wv * 16 + it;
    int n = n0 + tok;
    float4 zv = *reinterpret_cast<const float4*>(z + (size_t)n * 256 + lane * 4);
    int cnt = ccnt[tok];
    int bk = 0;
    if (cnt > MAXC) {  // overflow safety net: exact scan of all K
      float bs = 3.4e38f;
      for (int k = 0; k < K; ++k) {
        float4 ev = *reinterpret_cast<const float4*>(cb + (size_t)k * 256 + lane * 4);
        float dp = zv.x * ev.x + zv.y * ev.y + zv.z * ev.z + zv.w * ev.w;
        #pragma unroll
        for (int off = 32; off; off >>= 1) dp += __shfl_xor(dp, off, 64);
        float s = ee[k] - 2.f * dp;
        if (s < bs) { bs = s; bk = k; }
      }
    } else {
      unsigned pm = umin[tok];
      float thr = __uint_as_float(pm & 0xFFFFFC00u)
                + 1.63f + 0.002f * znorm[tok] * enmax;
      int c = (lane < cnt) ? lane : 0;
      unsigned pe = cand[tok * MAXC + c];
      bool flag = (lane < cnt) && (__uint_as_float(pe & 0xFFFFFC00u) <= thr);
      unsigned long long msk = __ballot(flag);
      if (__popcll(msk) == 1) {
        bk = (int)(pm & 1023u);   // unique in-margin candidate == exact argmin
      } else {
        float bs = 3.4e38f; bk = 1 << 29;
        while (msk) {
          int cc = __ffsll(msk) - 1;
          msk &= msk - 1;
          unsigned pc = cand[tok * MAXC + cc];
          int k = (int)(pc & 1023u);
          float4 ev = *reinterpret_cast<const float4*>(cb + (size_t)k * 256 + lane * 4);
          float dp = zv.x * ev.x + zv.y * ev.y + zv.z * ev.z + zv.w * ev.w;
          #pragma unroll
          for (int off = 32; off; off >>= 1) dp += __shfl_xor(dp, off, 64);
          float s = ee[k] - 2.f * dp;   // identical on all lanes
          if (s < bs || (s == bs && k < bk)) { bs = s; bk = k; }
        }
      }
    }
    float m = mask[n];
    float4 qv = *reinterpret_cast<const float4*>(cb + (size_t)bk * 256 + lane * 4);
    float4 o; o.x = qv.x * m; o.y = qv.y * m; o.z = qv.z * m; o.w = qv.w * m;
    *reinterpret_cast<float4*>(out_q + (size_t)n * 256 + lane * 4) = o;
    float dx = zv.x - qv.x, dy = zv.y - qv.y, dz = zv.z - qv.z, dw = zv.w - qv.w;
    lsum = fmaf(m, dx * dx + dy * dy + dz * dz + dw * dw, lsum);
    if (lane == 0) {
      msum += m;
      out_idx_f[n] = (m > 0.f) ? (float)bk : 0.f;
    }
  }
  #pragma unroll
  for (int off = 32; off; off >>= 1) lsum += __shfl_down(lsum, off, 64);
  if (lane == 0) { red[wv] = lsum; red[4 + wv] = msum; }
  __syncthreads();
  if (t == 0) {
    atomicAdd(&acc2[0], red[0] + red[1] + red[2] + red[3]);
    atomicAdd(&acc2[1], red[4] + red[5] + red[6] + red[7]);
    __threadfence();
    int prev = atomicAdd(done_ctr, 1);
    last = (prev == nblocks - 1);
  }
  __syncthreads();
  if (last && t == 0) {
    float s  = atomicAdd(&acc2[0], 0.0f);
    float nv = atomicAdd(&acc2[1], 0.0f);
    out_loss[0] = (nv > 0.f) ? (0.25f * s / (nv * 256.0f)) : 0.0f;
  }
}

// ---------------------------------------------------------------------------
extern "C" void kernel_launch(void* const* d_in, const int* in_sizes, int n_in,
                              void* d_out, int out_size, void* d_ws, size_t ws_size,
                              hipStream_t stream) {
  const float* z    = (const float*)d_in[0];  // (N, 256)
  const float* mask = (const float*)d_in[1];  // (N,)
  const float* cb   = (const float*)d_in[2];  // (K, 256)
  const int N = in_sizes[1];                  // 32768
  const int D = 256;
  const int K = in_sizes[2] / D;              // 1024

  float* wsf  = (float*)d_ws;
  float* acc2 = wsf;                          // 2 floats
  int*   dctr = (int*)(wsf + 2);              // 1 int
  float* ee   = wsf + 8;                      // K floats
  unsigned short* cb_bf = (unsigned short*)(ee + K);  // K*256 bf16

  float* out_q     = (float*)d_out;           // N*D
  float* out_loss  = out_q + (size_t)N * D;   // 1
  float* out_idx_f = out_loss + 1;            // N

  vq_prep<<<(K + 3) / 4, 256, 0, stream>>>(cb, cb_bf, ee, acc2, dctr, K);
  vq_main<<<N / TOK, 256, 0, stream>>>(z, cb, cb_bf, ee, mask, out_q,
                                       out_idx_f, out_loss, acc2, dctr, N / TOK, K);
}

// Round 3
// 237.801 us; speedup vs baseline: 2.2408x; 2.2408x over previous
//
#include <hip/hip_runtime.h>
#include <cstdint>

typedef short bf16x8 __attribute__((ext_vector_type(8)));
typedef float f32x4  __attribute__((ext_vector_type(4)));

#define TOK    64         // tokens per block
#define PITCH  264        // ushorts/row (256 + 8 pad; 132 dw = 4 mod 32 -> b128 tiles banks)
#define HROWS  (64 * PITCH)   // one K-half chunk buffer (64 code rows)
#define MAXC   32

__device__ __forceinline__ unsigned short f2bf(float f) {
  unsigned u = __float_as_uint(f);
  return (unsigned short)((u + 0x7FFFu + ((u >> 16) & 1u)) >> 16);
}
__device__ __forceinline__ uint4 pack8(float4 a, float4 b) {
  uint4 u;
  u.x = (unsigned)f2bf(a.x) | ((unsigned)f2bf(a.y) << 16);
  u.y = (unsigned)f2bf(a.z) | ((unsigned)f2bf(a.w) << 16);
  u.z = (unsigned)f2bf(b.x) | ((unsigned)f2bf(b.y) << 16);
  u.w = (unsigned)f2bf(b.z) | ((unsigned)f2bf(b.w) << 16);
  return u;
}

// ---------------------------------------------------------------------------
// Prep: cb_bf = bf16(cb), ee = ||cb_k||^2. Block 0 zeroes global accumulators.
// ---------------------------------------------------------------------------
__global__ __launch_bounds__(256) void vq_prep(const float* __restrict__ cb,
                                               unsigned short* __restrict__ cb_bf,
                                               float* __restrict__ ee,
                                               float* __restrict__ acc2,
                                               int* __restrict__ done_ctr, int K) {
  if (blockIdx.x == 0 && threadIdx.x == 0) {
    acc2[0] = 0.f; acc2[1] = 0.f; *done_ctr = 0;
  }
  int wave = threadIdx.x >> 6, lane = threadIdx.x & 63;
  int k = blockIdx.x * 4 + wave;
  if (k >= K) return;
  float4 v = *reinterpret_cast<const float4*>(cb + (size_t)k * 256 + lane * 4);
  float s = v.x * v.x + v.y * v.y + v.z * v.z + v.w * v.w;
  #pragma unroll
  for (int off = 32; off; off >>= 1) s += __shfl_down(s, off, 64);
  ushort4 b;
  b.x = f2bf(v.x); b.y = f2bf(v.y); b.z = f2bf(v.z); b.w = f2bf(v.w);
  *reinterpret_cast<ushort4*>(cb_bf + (size_t)k * 256 + lane * 4) = b;
  if (lane == 0) ee[k] = s;
}

// ---------------------------------------------------------------------------
// Main: 256 thr (4 waves), TOK=64, grid 512 -> 2 blocks/CU (LDS 76.8 KB).
// Exact R0 structure (122 us proven: chunk=64, per-half amin gate, margin
// 1.5, ushort cand MAXC=32, ee in LDS, plain rescore epilogue) + ONE change:
// T14 register-prefetch of chunk lc+1 (16 x uint4/thread via the 128-thread
// half-group) issued BEFORE chunk lc's MFMA+screen, ds_write after the read
// barrier. Hides the per-chunk L2 staging latency under compute.
// DO NOT use 512-thread blocks (VGPR crushed to 64, 40-reg spill, WRITE_SIZE
// 33->290 MB). DO NOT shrink MAXC or loosen the gate: overflow tokens cost
// ~60k cycles each in the exact-scan fallback (R2: 4x blowup).
// ---------------------------------------------------------------------------
__global__ __launch_bounds__(256, 2) void vq_main(
    const float* __restrict__ z, const float* __restrict__ cb,
    const unsigned short* __restrict__ cb_bf, const float* __restrict__ ee,
    const float* __restrict__ mask,
    float* __restrict__ out_q, float* __restrict__ out_idx_f,
    float* __restrict__ out_loss, float* __restrict__ acc2,
    int* __restrict__ done_ctr, int nblocks, int K) {
  __shared__ __align__(16) unsigned short buf[128 * PITCH];  // 67584 B: z-stage, then 2 half-buffers
  __shared__ float ee_lds[1024];                             // 4 KB
  __shared__ float znorm[TOK];
  __shared__ int   ccnt[TOK];
  __shared__ unsigned short cand[TOK * MAXC];                // 4 KB
  __shared__ float red[8];
  __shared__ bool  last;

  const int t = threadIdx.x;
  const int n0 = blockIdx.x * TOK;
  const int q16 = t & 15;

  // ---- code norms into LDS ----
  ee_lds[t]       = ee[t];
  ee_lds[t + 256] = ee[t + 256];
  ee_lds[t + 512] = ee[t + 512];
  ee_lds[t + 768] = ee[t + 768];
  if (t < TOK) ccnt[t] = 0;

  // ---- stage z -> bf16 into buf rows 0..63; ||z|| ----
  #pragma unroll
  for (int pass = 0; pass < 4; ++pass) {
    int row = pass * 16 + (t >> 4);
    const float* zr = z + (size_t)(n0 + row) * 256;
    float ssq = 0.f;
    #pragma unroll
    for (int j = 0; j < 2; ++j) {
      float4 a = *reinterpret_cast<const float4*>(zr + q16 * 8 + j * 128);
      float4 b = *reinterpret_cast<const float4*>(zr + q16 * 8 + j * 128 + 4);
      ssq += a.x*a.x + a.y*a.y + a.z*a.z + a.w*a.w
           + b.x*b.x + b.y*b.y + b.z*b.z + b.w*b.w;
      *reinterpret_cast<uint4*>(&buf[row * PITCH + q16 * 8 + j * 128]) = pack8(a, b);
    }
    #pragma unroll
    for (int off = 1; off < 16; off <<= 1) ssq += __shfl_xor(ssq, off, 64);
    if (q16 == 0) znorm[row] = sqrtf(ssq);
  }
  __syncthreads();  // S1: z staged

  // ---- A fragments into registers ----
  const int wv = t >> 6, lane = t & 63;
  const int p = wv & 1, kh = wv >> 1;
  const int quad = lane >> 4, l15 = lane & 15;
  bf16x8 afrag[2][8];
  float  znreg[2][4];
  #pragma unroll
  for (int s = 0; s < 2; ++s) {
    const unsigned short* za = &buf[(p * 32 + s * 16 + l15) * PITCH + quad * 8];
    #pragma unroll
    for (int kk = 0; kk < 8; ++kk)
      afrag[s][kk] = *reinterpret_cast<const bf16x8*>(za + kk * 32);
    #pragma unroll
    for (int r = 0; r < 4; ++r)
      znreg[s][r] = znorm[p * 32 + s * 16 + quad * 4 + r];
  }
  __syncthreads();  // S2: all A-loads done before chunk staging overwrites buf

  float amin[2][4];
  #pragma unroll
  for (int s = 0; s < 2; ++s)
    #pragma unroll
    for (int r = 0; r < 4; ++r) amin[s][r] = 3.4e38f;

  // half-group staging identity: 128 threads (both p-waves of this K-half)
  const int tq = (p << 6) | lane;           // 0..127 within half-group
  const int sq16 = tq & 15, srow = tq >> 4; // 16 lanes/row, 8 rows/pass
  unsigned short* qbuf = &buf[kh * HROWS];

  // ---- prologue: chunk 0 -> regs -> LDS ----
  uint4 st[16];
  {
    const unsigned short* base = cb_bf + (size_t)kh * 512 * 256;
    #pragma unroll
    for (int pass = 0; pass < 8; ++pass) {
      const unsigned short* src = base + (size_t)(pass * 8 + srow) * 256 + sq16 * 8;
      st[pass * 2]     = *reinterpret_cast<const uint4*>(src);
      st[pass * 2 + 1] = *reinterpret_cast<const uint4*>(src + 128);
    }
    #pragma unroll
    for (int pass = 0; pass < 8; ++pass) {
      int row = pass * 8 + srow;
      *reinterpret_cast<uint4*>(&qbuf[row * PITCH + sq16 * 8])       = st[pass * 2];
      *reinterpret_cast<uint4*>(&qbuf[row * PITCH + sq16 * 8 + 128]) = st[pass * 2 + 1];
    }
  }
  __syncthreads();  // S3: chunk 0 visible

  // ---- chunk loop: 8 chunks x 64 codes per K-half ----
  for (int lc = 0; lc < 8; ++lc) {
    const int kbase = kh * 512 + lc * 64;
    if (lc < 7) {  // T14: issue next chunk's global loads before compute
      const unsigned short* base = cb_bf + (size_t)(kh * 512 + (lc + 1) * 64) * 256;
      #pragma unroll
      for (int pass = 0; pass < 8; ++pass) {
        const unsigned short* src = base + (size_t)(pass * 8 + srow) * 256 + sq16 * 8;
        st[pass * 2]     = *reinterpret_cast<const uint4*>(src);
        st[pass * 2 + 1] = *reinterpret_cast<const uint4*>(src + 128);
      }
    }

    f32x4 acc[2][4];
    #pragma unroll
    for (int s = 0; s < 2; ++s)
      #pragma unroll
      for (int ct = 0; ct < 4; ++ct) acc[s][ct] = (f32x4){0.f, 0.f, 0.f, 0.f};
    __builtin_amdgcn_s_setprio(1);
    #pragma unroll
    for (int kk = 0; kk < 8; ++kk) {
      bf16x8 b0 = *reinterpret_cast<const bf16x8*>(&qbuf[(l15)      * PITCH + quad * 8 + kk * 32]);
      bf16x8 b1 = *reinterpret_cast<const bf16x8*>(&qbuf[(16 + l15) * PITCH + quad * 8 + kk * 32]);
      bf16x8 b2 = *reinterpret_cast<const bf16x8*>(&qbuf[(32 + l15) * PITCH + quad * 8 + kk * 32]);
      bf16x8 b3 = *reinterpret_cast<const bf16x8*>(&qbuf[(48 + l15) * PITCH + quad * 8 + kk * 32]);
      acc[0][0] = __builtin_amdgcn_mfma_f32_16x16x32_bf16(afrag[0][kk], b0, acc[0][0], 0, 0, 0);
      acc[1][0] = __builtin_amdgcn_mfma_f32_16x16x32_bf16(afrag[1][kk], b0, acc[1][0], 0, 0, 0);
      acc[0][1] = __builtin_amdgcn_mfma_f32_16x16x32_bf16(afrag[0][kk], b1, acc[0][1], 0, 0, 0);
      acc[1][1] = __builtin_amdgcn_mfma_f32_16x16x32_bf16(afrag[1][kk], b1, acc[1][1], 0, 0, 0);
      acc[0][2] = __builtin_amdgcn_mfma_f32_16x16x32_bf16(afrag[0][kk], b2, acc[0][2], 0, 0, 0);
      acc[1][2] = __builtin_amdgcn_mfma_f32_16x16x32_bf16(afrag[1][kk], b2, acc[1][2], 0, 0, 0);
      acc[0][3] = __builtin_amdgcn_mfma_f32_16x16x32_bf16(afrag[0][kk], b3, acc[0][3], 0, 0, 0);
      acc[1][3] = __builtin_amdgcn_mfma_f32_16x16x32_bf16(afrag[1][kk], b3, acc[1][3], 0, 0, 0);
    }
    __builtin_amdgcn_s_setprio(0);

    float e0 = ee_lds[kbase + l15],      e1 = ee_lds[kbase + 16 + l15];
    float e2 = ee_lds[kbase + 32 + l15], e3 = ee_lds[kbase + 48 + l15];
    float en0 = sqrtf(e0), en1 = sqrtf(e1), en2 = sqrtf(e2), en3 = sqrtf(e3);
    #pragma unroll
    for (int s = 0; s < 2; ++s) {
      #pragma unroll
      for (int r = 0; r < 4; ++r) {
        float d0 = e0 - 2.f * acc[s][0][r];
        float d1 = e1 - 2.f * acc[s][1][r];
        float d2 = e2 - 2.f * acc[s][2][r];
        float d3 = e3 - 2.f * acc[s][3][r];
        float w = fminf(fminf(d0, d1), fminf(d2, d3));
        #pragma unroll
        for (int off = 1; off < 16; off <<= 1) w = fminf(w, __shfl_xor(w, off, 64));
        float am = fminf(amin[s][r], w);
        amin[s][r] = am;
        int tok = p * 32 + s * 16 + quad * 4 + r;
        float zn = znreg[s][r];
        // margin >= 2*eps(bf16 screen); half-local amin keeps the same bound
        if (d0 <= am + 1.5f + 0.002f * zn * en0) {
          int sl = atomicAdd(&ccnt[tok], 1);
          if (sl < MAXC) cand[tok * MAXC + sl] = (unsigned short)(kbase + l15);
        }
        if (d1 <= am + 1.5f + 0.002f * zn * en1) {
          int sl = atomicAdd(&ccnt[tok], 1);
          if (sl < MAXC) cand[tok * MAXC + sl] = (unsigned short)(kbase + 16 + l15);
        }
        if (d2 <= am + 1.5f + 0.002f * zn * en2) {
          int sl = atomicAdd(&ccnt[tok], 1);
          if (sl < MAXC) cand[tok * MAXC + sl] = (unsigned short)(kbase + 32 + l15);
        }
        if (d3 <= am + 1.5f + 0.002f * zn * en3) {
          int sl = atomicAdd(&ccnt[tok], 1);
          if (sl < MAXC) cand[tok * MAXC + sl] = (unsigned short)(kbase + 48 + l15);
        }
      }
    }
    __syncthreads();  // all reads of qbuf done across half-group
    if (lc < 7) {     // write prefetched chunk into LDS, publish
      #pragma unroll
      for (int pass = 0; pass < 8; ++pass) {
        int row = pass * 8 + srow;
        *reinterpret_cast<uint4*>(&qbuf[row * PITCH + sq16 * 8])       = st[pass * 2];
        *reinterpret_cast<uint4*>(&qbuf[row * PITCH + sq16 * 8 + 128]) = st[pass * 2 + 1];
      }
      __syncthreads();
    }
  }

  // ---- exact fp32 rescore + epilogue: 4 waves x 16 tokens ----
  float lsum = 0.f, msum = 0.f;
  for (int it = 0; it < 16; ++it) {
    int tok = wv * 16 + it;
    int n = n0 + tok;
    float4 zv = *reinterpret_cast<const float4*>(z + (size_t)n * 256 + lane * 4);
    int cnt = ccnt[tok];
    float bs = 3.4e38f; int bk = 0;
    if (cnt > MAXC) {  // overflow safety net: exact scan of all K
      for (int k = 0; k < K; ++k) {
        float4 ev = *reinterpret_cast<const float4*>(cb + (size_t)k * 256 + lane * 4);
        float dp = zv.x * ev.x + zv.y * ev.y + zv.z * ev.z + zv.w * ev.w;
        #pragma unroll
        for (int off = 32; off; off >>= 1) dp += __shfl_xor(dp, off, 64);
        float s = ee_lds[k] - 2.f * dp;
        if (s < bs) { bs = s; bk = k; }
      }
    } else {
      for (int c = 0; c < cnt; ++c) {
        int k = cand[tok * MAXC + c];
        float4 ev = *reinterpret_cast<const float4*>(cb + (size_t)k * 256 + lane * 4);
        float dp = zv.x * ev.x + zv.y * ev.y + zv.z * ev.z + zv.w * ev.w;
        #pragma unroll
        for (int off = 32; off; off >>= 1) dp += __shfl_xor(dp, off, 64);
        float s = ee_lds[k] - 2.f * dp;   // identical on all lanes
        if (s < bs || (s == bs && k < bk)) { bs = s; bk = k; }
      }
    }
    float m = mask[n];
    float4 qv = *reinterpret_cast<const float4*>(cb + (size_t)bk * 256 + lane * 4);
    float4 o; o.x = qv.x * m; o.y = qv.y * m; o.z = qv.z * m; o.w = qv.w * m;
    *reinterpret_cast<float4*>(out_q + (size_t)n * 256 + lane * 4) = o;
    float dx = zv.x - qv.x, dy = zv.y - qv.y, dz = zv.z - qv.z, dw = zv.w - qv.w;
    lsum = fmaf(m, dx * dx + dy * dy + dz * dz + dw * dw, lsum);
    if (lane == 0) {
      msum += m;
      out_idx_f[n] = (m > 0.f) ? (float)bk : 0.f;
    }
  }
  #pragma unroll
  for (int off = 32; off; off >>= 1) lsum += __shfl_down(lsum, off, 64);
  if (lane == 0) { red[wv] = lsum; red[4 + wv] = msum; }
  __syncthreads();
  if (t == 0) {
    atomicAdd(&acc2[0], red[0] + red[1] + red[2] + red[3]);
    atomicAdd(&acc2[1], red[4] + red[5] + red[6] + red[7]);
    __threadfence();
    int prev = atomicAdd(done_ctr, 1);
    last = (prev == nblocks - 1);
  }
  __syncthreads();
  if (last && t == 0) {
    float s  = atomicAdd(&acc2[0], 0.0f);
    float nv = atomicAdd(&acc2[1], 0.0f);
    out_loss[0] = (nv > 0.f) ? (0.25f * s / (nv * 256.0f)) : 0.0f;
  }
}

// ---------------------------------------------------------------------------
extern "C" void kernel_launch(void* const* d_in, const int* in_sizes, int n_in,
                              void* d_out, int out_size, void* d_ws, size_t ws_size,
                              hipStream_t stream) {
  const float* z    = (const float*)d_in[0];  // (N, 256)
  const float* mask = (const float*)d_in[1];  // (N,)
  const float* cb   = (const float*)d_in[2];  // (K, 256)
  const int N = in_sizes[1];                  // 32768
  const int D = 256;
  const int K = in_sizes[2] / D;              // 1024

  float* wsf  = (float*)d_ws;
  float* acc2 = wsf;                          // 2 floats
  int*   dctr = (int*)(wsf + 2);              // 1 int
  float* ee   = wsf + 8;                      // K floats
  unsigned short* cb_bf = (unsigned short*)(ee + K);  // K*256 bf16

  float* out_q     = (float*)d_out;           // N*D
  float* out_loss  = out_q + (size_t)N * D;   // 1
  float* out_idx_f = out_loss + 1;            // N

  vq_prep<<<(K + 3) / 4, 256, 0, stream>>>(cb, cb_bf, ee, acc2, dctr, K);
  vq_main<<<N / TOK, 256, 0, stream>>>(z, cb, cb_bf, ee, mask, out_q,
                                       out_idx_f, out_loss, acc2, dctr, N / TOK, K);
}

// Round 4
// 182.781 us; speedup vs baseline: 2.9154x; 1.3010x over previous
//
#include <hip/hip_runtime.h>
#include <cstdint>

typedef short bf16x8 __attribute__((ext_vector_type(8)));
typedef float f32x4  __attribute__((ext_vector_type(4)));

#define TOK    64         // tokens per block
#define CH     64         // codes per chunk
#define NCH    16         // chunks (K=1024)
#define BUFW   16384      // ushorts per chunk buffer (64 rows x 256)
#define MAXC   32

__device__ __forceinline__ unsigned short f2bf(float f) {
  unsigned u = __float_as_uint(f);
  return (unsigned short)((u + 0x7FFFu + ((u >> 16) & 1u)) >> 16);
}
__device__ __forceinline__ uint4 pack8(float4 a, float4 b) {
  uint4 u;
  u.x = (unsigned)f2bf(a.x) | ((unsigned)f2bf(a.y) << 16);
  u.y = (unsigned)f2bf(a.z) | ((unsigned)f2bf(a.w) << 16);
  u.z = (unsigned)f2bf(b.x) | ((unsigned)f2bf(b.y) << 16);
  u.w = (unsigned)f2bf(b.z) | ((unsigned)f2bf(b.w) << 16);
  return u;
}
// async global->LDS DMA, 16 B per lane. LDS dest must be wave-uniform base
// (HW adds lane*16); global src is per-lane. Zero VGPR staging cost.
__device__ __forceinline__ void gload16(const unsigned short* g, unsigned short* l) {
  __builtin_amdgcn_global_load_lds(
      (const __attribute__((address_space(1))) unsigned int*)(const void*)g,
      (__attribute__((address_space(3))) unsigned int*)(void*)l, 16, 0, 0);
}

// ---------------------------------------------------------------------------
// Prep: cb_bf = bf16(cb), ee = ||cb_k||^2. Block 0 zeroes global accumulators.
// ---------------------------------------------------------------------------
__global__ __launch_bounds__(256) void vq_prep(const float* __restrict__ cb,
                                               unsigned short* __restrict__ cb_bf,
                                               float* __restrict__ ee,
                                               float* __restrict__ acc2,
                                               int* __restrict__ done_ctr, int K) {
  if (blockIdx.x == 0 && threadIdx.x == 0) {
    acc2[0] = 0.f; acc2[1] = 0.f; *done_ctr = 0;
  }
  int wave = threadIdx.x >> 6, lane = threadIdx.x & 63;
  int k = blockIdx.x * 4 + wave;
  if (k >= K) return;
  float4 v = *reinterpret_cast<const float4*>(cb + (size_t)k * 256 + lane * 4);
  float s = v.x * v.x + v.y * v.y + v.z * v.z + v.w * v.w;
  #pragma unroll
  for (int off = 32; off; off >>= 1) s += __shfl_down(s, off, 64);
  ushort4 b;
  b.x = f2bf(v.x); b.y = f2bf(v.y); b.z = f2bf(v.z); b.w = f2bf(v.w);
  *reinterpret_cast<ushort4*>(cb_bf + (size_t)k * 256 + lane * 4) = b;
  if (lane == 0) ee[k] = s;
}

// ---------------------------------------------------------------------------
// Main: 256 thr (4 waves), TOK=64, grid 512 -> 2 blocks/CU (LDS ~74.3 KB).
// Each wave owns 16 tokens x ALL 1024 codes (16 chunks of 64). Chunk staging
// via double-buffered __builtin_amdgcn_global_load_lds (async DMA, no VGPR):
// issue chunk lc+1's 8 gloads/wave -> MFMA+screen chunk lc -> vmcnt(0) ->
// one barrier. This removes R0's serialized load/waitcnt/ds_write staging
// (~6.4k cy/chunk, the dominant cost at 122 us).
// LDS layout is LINEAR (global_load_lds requirement); bank spread via XOR
// granule swizzle: physical 16B-granule = logical ^ (row&7), applied as
// inverse swizzle on the per-lane GLOBAL source + same XOR on every LDS read
// (both-sides rule). Distribution is bank-uniform.
// DO NOT: 512-thread blocks (VGPR crush + spill); register prefetch arrays
// (R3: st[16] spilled, 286 MB scratch); MAXC<32 or looser margin (R2: 4x).
// ---------------------------------------------------------------------------
__global__ __launch_bounds__(256, 2) void vq_main(
    const float* __restrict__ z, const float* __restrict__ cb,
    const unsigned short* __restrict__ cb_bf, const float* __restrict__ ee,
    const float* __restrict__ mask,
    float* __restrict__ out_q, float* __restrict__ out_idx_f,
    float* __restrict__ out_loss, float* __restrict__ acc2,
    int* __restrict__ done_ctr, int nblocks, int K) {
  __shared__ __align__(16) unsigned short sbuf[2 * BUFW];    // 64 KB: dbuf chunks; buf0 doubles as z-stage
  __shared__ float ee_lds[1024];                             // 4 KB
  __shared__ float znorm[TOK];
  __shared__ int   ccnt[TOK];
  __shared__ unsigned short cand[TOK * MAXC];                // 4 KB
  __shared__ float red[8];
  __shared__ bool  last;

  const int t = threadIdx.x;
  const int n0 = blockIdx.x * TOK;
  const int wv = t >> 6, lane = t & 63;
  const int quad = lane >> 4, l15 = lane & 15;
  const int q16 = t & 15;

  // ---- code norms into LDS ----
  ee_lds[t]       = ee[t];
  ee_lds[t + 256] = ee[t + 256];
  ee_lds[t + 512] = ee[t + 512];
  ee_lds[t + 768] = ee[t + 768];
  if (t < TOK) ccnt[t] = 0;

  // ---- stage z -> bf16 into buf0 rows 0..63 (swizzled); ||z|| ----
  #pragma unroll
  for (int pass = 0; pass < 4; ++pass) {
    int row = pass * 16 + (t >> 4);
    const float* zr = z + (size_t)(n0 + row) * 256;
    float ssq = 0.f;
    #pragma unroll
    for (int j = 0; j < 2; ++j) {
      float4 a = *reinterpret_cast<const float4*>(zr + q16 * 16 + j * 8);
      float4 b = *reinterpret_cast<const float4*>(zr + q16 * 16 + j * 8 + 4);
      ssq += a.x*a.x + a.y*a.y + a.z*a.z + a.w*a.w
           + b.x*b.x + b.y*b.y + b.z*b.z + b.w*b.w;
      int g = q16 * 2 + j;                       // logical granule 0..31
      *reinterpret_cast<uint4*>(&sbuf[row * 256 + ((g ^ (row & 7)) * 8)]) = pack8(a, b);
    }
    #pragma unroll
    for (int off = 1; off < 16; off <<= 1) ssq += __shfl_xor(ssq, off, 64);
    if (q16 == 0) znorm[row] = sqrtf(ssq);
  }
  __syncthreads();  // S1: z staged

  // ---- A fragments into registers: wave wv owns token rows wv*16 + l15 ----
  bf16x8 afrag[8];
  float  znreg[4];
  {
    int row = wv * 16 + l15;
    #pragma unroll
    for (int kk = 0; kk < 8; ++kk) {
      int g = (quad + kk * 4) ^ (row & 7);
      afrag[kk] = *reinterpret_cast<const bf16x8*>(&sbuf[row * 256 + g * 8]);
    }
    #pragma unroll
    for (int r = 0; r < 4; ++r)
      znreg[r] = znorm[wv * 16 + quad * 4 + r];
  }
  __syncthreads();  // S2: all A-loads done before chunk 0 overwrites buf0

  // ---- prologue: issue chunk 0 -> buf0 (async DMA), wait, publish ----
  {
    #pragma unroll
    for (int i = 0; i < 8; ++i) {
      int f = (wv * 8 + i) * 64 + lane;          // granule 0..2047
      int row = f >> 5, slot = f & 31;
      gload16(cb_bf + (size_t)row * 256 + ((slot ^ (row & 7)) * 8),
              &sbuf[(size_t)(wv * 512 + i * 64) * 8]);
    }
  }
  asm volatile("s_waitcnt vmcnt(0)" ::: "memory");
  __syncthreads();  // S3: chunk 0 visible

  float amin[4] = {3.4e38f, 3.4e38f, 3.4e38f, 3.4e38f};

  // ---- chunk loop: 16 chunks x 64 codes, double-buffered async staging ----
  for (int lc = 0; lc < NCH; ++lc) {
    const int kbase = lc * CH;
    unsigned short* cur = &sbuf[(lc & 1) * BUFW];
    unsigned short* nxt = &sbuf[((lc + 1) & 1) * BUFW];
    if (lc < NCH - 1) {  // issue next chunk's DMA before compute
      const unsigned short* base = cb_bf + (size_t)(kbase + CH) * 256;
      #pragma unroll
      for (int i = 0; i < 8; ++i) {
        int f = (wv * 8 + i) * 64 + lane;
        int row = f >> 5, slot = f & 31;
        gload16(base + (size_t)row * 256 + ((slot ^ (row & 7)) * 8),
                nxt + (size_t)(wv * 512 + i * 64) * 8);
      }
    }

    f32x4 acc[4];
    #pragma unroll
    for (int ct = 0; ct < 4; ++ct) acc[ct] = (f32x4){0.f, 0.f, 0.f, 0.f};
    __builtin_amdgcn_s_setprio(1);
    #pragma unroll
    for (int kk = 0; kk < 8; ++kk) {
      int gx = quad + kk * 4;
      bf16x8 b0 = *reinterpret_cast<const bf16x8*>(&cur[(l15)      * 256 + ((gx ^ ( l15       & 7)) * 8)]);
      bf16x8 b1 = *reinterpret_cast<const bf16x8*>(&cur[(16 + l15) * 256 + ((gx ^ ((16 + l15) & 7)) * 8)]);
      bf16x8 b2 = *reinterpret_cast<const bf16x8*>(&cur[(32 + l15) * 256 + ((gx ^ ((32 + l15) & 7)) * 8)]);
      bf16x8 b3 = *reinterpret_cast<const bf16x8*>(&cur[(48 + l15) * 256 + ((gx ^ ((48 + l15) & 7)) * 8)]);
      acc[0] = __builtin_amdgcn_mfma_f32_16x16x32_bf16(afrag[kk], b0, acc[0], 0, 0, 0);
      acc[1] = __builtin_amdgcn_mfma_f32_16x16x32_bf16(afrag[kk], b1, acc[1], 0, 0, 0);
      acc[2] = __builtin_amdgcn_mfma_f32_16x16x32_bf16(afrag[kk], b2, acc[2], 0, 0, 0);
      acc[3] = __builtin_amdgcn_mfma_f32_16x16x32_bf16(afrag[kk], b3, acc[3], 0, 0, 0);
    }
    __builtin_amdgcn_s_setprio(0);

    float e0 = ee_lds[kbase + l15],      e1 = ee_lds[kbase + 16 + l15];
    float e2 = ee_lds[kbase + 32 + l15], e3 = ee_lds[kbase + 48 + l15];
    float en0 = sqrtf(e0), en1 = sqrtf(e1), en2 = sqrtf(e2), en3 = sqrtf(e3);
    #pragma unroll
    for (int r = 0; r < 4; ++r) {
      float d0 = e0 - 2.f * acc[0][r];
      float d1 = e1 - 2.f * acc[1][r];
      float d2 = e2 - 2.f * acc[2][r];
      float d3 = e3 - 2.f * acc[3][r];
      float w = fminf(fminf(d0, d1), fminf(d2, d3));
      #pragma unroll
      for (int off = 1; off < 16; off <<= 1) w = fminf(w, __shfl_xor(w, off, 64));
      float am = fminf(amin[r], w);
      amin[r] = am;
      int tok = wv * 16 + quad * 4 + r;
      float zn = znreg[r];
      // margin >= 2*eps(bf16 screen); full-K running amin keeps the bound
      if (d0 <= am + 1.5f + 0.002f * zn * en0) {
        int sl = atomicAdd(&ccnt[tok], 1);
        if (sl < MAXC) cand[tok * MAXC + sl] = (unsigned short)(kbase + l15);
      }
      if (d1 <= am + 1.5f + 0.002f * zn * en1) {
        int sl = atomicAdd(&ccnt[tok], 1);
        if (sl < MAXC) cand[tok * MAXC + sl] = (unsigned short)(kbase + 16 + l15);
      }
      if (d2 <= am + 1.5f + 0.002f * zn * en2) {
        int sl = atomicAdd(&ccnt[tok], 1);
        if (sl < MAXC) cand[tok * MAXC + sl] = (unsigned short)(kbase + 32 + l15);
      }
      if (d3 <= am + 1.5f + 0.002f * zn * en3) {
        int sl = atomicAdd(&ccnt[tok], 1);
        if (sl < MAXC) cand[tok * MAXC + sl] = (unsigned short)(kbase + 48 + l15);
      }
    }
    asm volatile("s_waitcnt vmcnt(0)" ::: "memory");  // next-chunk DMA landed
    __syncthreads();                                  // visible to all waves
  }

  // ---- exact fp32 rescore + epilogue: 4 waves x 16 tokens ----
  float lsum = 0.f, msum = 0.f;
  for (int it = 0; it < 16; ++it) {
    int tok = wv * 16 + it;
    int n = n0 + tok;
    float4 zv = *reinterpret_cast<const float4*>(z + (size_t)n * 256 + lane * 4);
    int cnt = ccnt[tok];
    float bs = 3.4e38f; int bk = 0;
    if (cnt > MAXC) {  // overflow safety net: exact scan of all K
      for (int k = 0; k < K; ++k) {
        float4 ev = *reinterpret_cast<const float4*>(cb + (size_t)k * 256 + lane * 4);
        float dp = zv.x * ev.x + zv.y * ev.y + zv.z * ev.z + zv.w * ev.w;
        #pragma unroll
        for (int off = 32; off; off >>= 1) dp += __shfl_xor(dp, off, 64);
        float s = ee_lds[k] - 2.f * dp;
        if (s < bs) { bs = s; bk = k; }
      }
    } else {
      for (int c = 0; c < cnt; ++c) {
        int k = cand[tok * MAXC + c];
        float4 ev = *reinterpret_cast<const float4*>(cb + (size_t)k * 256 + lane * 4);
        float dp = zv.x * ev.x + zv.y * ev.y + zv.z * ev.z + zv.w * ev.w;
        #pragma unroll
        for (int off = 32; off; off >>= 1) dp += __shfl_xor(dp, off, 64);
        float s = ee_lds[k] - 2.f * dp;   // identical on all lanes
        if (s < bs || (s == bs && k < bk)) { bs = s; bk = k; }
      }
    }
    float m = mask[n];
    float4 qv = *reinterpret_cast<const float4*>(cb + (size_t)bk * 256 + lane * 4);
    float4 o; o.x = qv.x * m; o.y = qv.y * m; o.z = qv.z * m; o.w = qv.w * m;
    *reinterpret_cast<float4*>(out_q + (size_t)n * 256 + lane * 4) = o;
    float dx = zv.x - qv.x, dy = zv.y - qv.y, dz = zv.z - qv.z, dw = zv.w - qv.w;
    lsum = fmaf(m, dx * dx + dy * dy + dz * dz + dw * dw, lsum);
    if (lane == 0) {
      msum += m;
      out_idx_f[n] = (m > 0.f) ? (float)bk : 0.f;
    }
  }
  #pragma unroll
  for (int off = 32; off; off >>= 1) lsum += __shfl_down(lsum, off, 64);
  if (lane == 0) { red[wv] = lsum; red[4 + wv] = msum; }
  __syncthreads();
  if (t == 0) {
    atomicAdd(&acc2[0], red[0] + red[1] + red[2] + red[3]);
    atomicAdd(&acc2[1], red[4] + red[5] + red[6] + red[7]);
    __threadfence();
    int prev = atomicAdd(done_ctr, 1);
    last = (prev == nblocks - 1);
  }
  __syncthreads();
  if (last && t == 0) {
    float s  = atomicAdd(&acc2[0], 0.0f);
    float nv = atomicAdd(&acc2[1], 0.0f);
    out_loss[0] = (nv > 0.f) ? (0.25f * s / (nv * 256.0f)) : 0.0f;
  }
}

// ---------------------------------------------------------------------------
extern "C" void kernel_launch(void* const* d_in, const int* in_sizes, int n_in,
                              void* d_out, int out_size, void* d_ws, size_t ws_size,
                              hipStream_t stream) {
  const float* z    = (const float*)d_in[0];  // (N, 256)
  const float* mask = (const float*)d_in[1];  // (N,)
  const float* cb   = (const float*)d_in[2];  // (K, 256)
  const int N = in_sizes[1];                  // 32768
  const int D = 256;
  const int K = in_sizes[2] / D;              // 1024

  float* wsf  = (float*)d_ws;
  float* acc2 = wsf;                          // 2 floats
  int*   dctr = (int*)(wsf + 2);              // 1 int
  float* ee   = wsf + 8;                      // K floats
  unsigned short* cb_bf = (unsigned short*)(ee + K);  // K*256 bf16

  float* out_q     = (float*)d_out;           // N*D
  float* out_loss  = out_q + (size_t)N * D;   // 1
  float* out_idx_f = out_loss + 1;            // N

  vq_prep<<<(K + 3) / 4, 256, 0, stream>>>(cb, cb_bf, ee, acc2, dctr, K);
  vq_main<<<N / TOK, 256, 0, stream>>>(z, cb, cb_bf, ee, mask, out_q,
                                       out_idx_f, out_loss, acc2, dctr, N / TOK, K);
}

// Round 5
// 175.790 us; speedup vs baseline: 3.0313x; 1.0398x over previous
//
#include <hip/hip_runtime.h>
#include <cstdint>

typedef short bf16x8 __attribute__((ext_vector_type(8)));
typedef float f32x4  __attribute__((ext_vector_type(4)));

#define TOK    64         // tokens per block
#define CH     64         // codes per chunk
#define NCH    16         // chunks (K=1024)
#define BUFW   16384      // ushorts per chunk buffer (64 rows x 256)
#define MAXC   32

__device__ __forceinline__ unsigned short f2bf(float f) {
  unsigned u = __float_as_uint(f);
  return (unsigned short)((u + 0x7FFFu + ((u >> 16) & 1u)) >> 16);
}
__device__ __forceinline__ uint4 pack8(float4 a, float4 b) {
  uint4 u;
  u.x = (unsigned)f2bf(a.x) | ((unsigned)f2bf(a.y) << 16);
  u.y = (unsigned)f2bf(a.z) | ((unsigned)f2bf(a.w) << 16);
  u.z = (unsigned)f2bf(b.x) | ((unsigned)f2bf(b.y) << 16);
  u.w = (unsigned)f2bf(b.z) | ((unsigned)f2bf(b.w) << 16);
  return u;
}
// async global->LDS DMA, 16 B per lane. LDS dest must be wave-uniform base
// (HW adds lane*16); global src is per-lane. Zero VGPR staging cost.
__device__ __forceinline__ void gload16(const unsigned short* g, unsigned short* l) {
  __builtin_amdgcn_global_load_lds(
      (const __attribute__((address_space(1))) unsigned int*)(const void*)g,
      (__attribute__((address_space(3))) unsigned int*)(void*)l, 16, 0, 0);
}

// ---------------------------------------------------------------------------
// Prep: cb_bf = bf16(cb), ee = ||cb_k||^2. Block 0 zeroes global accumulators.
// ---------------------------------------------------------------------------
__global__ __launch_bounds__(256) void vq_prep(const float* __restrict__ cb,
                                               unsigned short* __restrict__ cb_bf,
                                               float* __restrict__ ee,
                                               float* __restrict__ acc2,
                                               int* __restrict__ done_ctr, int K) {
  if (blockIdx.x == 0 && threadIdx.x == 0) {
    acc2[0] = 0.f; acc2[1] = 0.f; *done_ctr = 0;
  }
  int wave = threadIdx.x >> 6, lane = threadIdx.x & 63;
  int k = blockIdx.x * 4 + wave;
  if (k >= K) return;
  float4 v = *reinterpret_cast<const float4*>(cb + (size_t)k * 256 + lane * 4);
  float s = v.x * v.x + v.y * v.y + v.z * v.z + v.w * v.w;
  #pragma unroll
  for (int off = 32; off; off >>= 1) s += __shfl_down(s, off, 64);
  ushort4 b;
  b.x = f2bf(v.x); b.y = f2bf(v.y); b.z = f2bf(v.z); b.w = f2bf(v.w);
  *reinterpret_cast<ushort4*>(cb_bf + (size_t)k * 256 + lane * 4) = b;
  if (lane == 0) ee[k] = s;
}

// ---------------------------------------------------------------------------
// Main: 256 thr (4 waves), TOK=64, grid 512 -> 2 blocks/CU (LDS ~74.5 KB).
// Chunk loop identical to R4 (async dbuf global_load_lds, XOR granule
// swizzle). Evidence R0/R3/R4 (122/184/131 us): staging mechanics are NOT
// the bottleneck; kernel is dependent-chain latency-bound (all pipes <20%).
// R5 change: EPILOGUE ILP. (a) candidate rescore unrolled x4 -> 4 global ev
// loads + 4 interleaved shuffle-reduce chains in flight (was 1 serial chain
// ~600cy per candidate); (b) output phase split off, unrolled x2 via bkbuf
// in LDS; (c) overflow fallback unrolled x2. Comparator preserved exactly
// (order-independent smallest-k tie-break) -> bit-identical results.
// DO NOT: 512-thread blocks (VGPR crush + spill); register prefetch arrays
// (R3: st[16] spilled, 286 MB scratch); MAXC<32 or looser margin (R2: 4x).
// ---------------------------------------------------------------------------
__global__ __launch_bounds__(256, 2) void vq_main(
    const float* __restrict__ z, const float* __restrict__ cb,
    const unsigned short* __restrict__ cb_bf, const float* __restrict__ ee,
    const float* __restrict__ mask,
    float* __restrict__ out_q, float* __restrict__ out_idx_f,
    float* __restrict__ out_loss, float* __restrict__ acc2,
    int* __restrict__ done_ctr, int nblocks, int K) {
  __shared__ __align__(16) unsigned short sbuf[2 * BUFW];    // 64 KB: dbuf chunks; buf0 doubles as z-stage
  __shared__ float ee_lds[1024];                             // 4 KB
  __shared__ float znorm[TOK];
  __shared__ int   ccnt[TOK];
  __shared__ unsigned short cand[TOK * MAXC];                // 4 KB
  __shared__ unsigned short bkbuf[TOK];                      // winner index per token
  __shared__ float red[8];
  __shared__ bool  last;

  const int t = threadIdx.x;
  const int n0 = blockIdx.x * TOK;
  const int wv = t >> 6, lane = t & 63;
  const int quad = lane >> 4, l15 = lane & 15;
  const int q16 = t & 15;

  // ---- code norms into LDS ----
  ee_lds[t]       = ee[t];
  ee_lds[t + 256] = ee[t + 256];
  ee_lds[t + 512] = ee[t + 512];
  ee_lds[t + 768] = ee[t + 768];
  if (t < TOK) ccnt[t] = 0;

  // ---- stage z -> bf16 into buf0 rows 0..63 (swizzled); ||z|| ----
  #pragma unroll
  for (int pass = 0; pass < 4; ++pass) {
    int row = pass * 16 + (t >> 4);
    const float* zr = z + (size_t)(n0 + row) * 256;
    float ssq = 0.f;
    #pragma unroll
    for (int j = 0; j < 2; ++j) {
      float4 a = *reinterpret_cast<const float4*>(zr + q16 * 16 + j * 8);
      float4 b = *reinterpret_cast<const float4*>(zr + q16 * 16 + j * 8 + 4);
      ssq += a.x*a.x + a.y*a.y + a.z*a.z + a.w*a.w
           + b.x*b.x + b.y*b.y + b.z*b.z + b.w*b.w;
      int g = q16 * 2 + j;                       // logical granule 0..31
      *reinterpret_cast<uint4*>(&sbuf[row * 256 + ((g ^ (row & 7)) * 8)]) = pack8(a, b);
    }
    #pragma unroll
    for (int off = 1; off < 16; off <<= 1) ssq += __shfl_xor(ssq, off, 64);
    if (q16 == 0) znorm[row] = sqrtf(ssq);
  }
  __syncthreads();  // S1: z staged

  // ---- A fragments into registers: wave wv owns token rows wv*16 + l15 ----
  bf16x8 afrag[8];
  float  znreg[4];
  {
    int row = wv * 16 + l15;
    #pragma unroll
    for (int kk = 0; kk < 8; ++kk) {
      int g = (quad + kk * 4) ^ (row & 7);
      afrag[kk] = *reinterpret_cast<const bf16x8*>(&sbuf[row * 256 + g * 8]);
    }
    #pragma unroll
    for (int r = 0; r < 4; ++r)
      znreg[r] = znorm[wv * 16 + quad * 4 + r];
  }
  __syncthreads();  // S2: all A-loads done before chunk 0 overwrites buf0

  // ---- prologue: issue chunk 0 -> buf0 (async DMA), wait, publish ----
  {
    #pragma unroll
    for (int i = 0; i < 8; ++i) {
      int f = (wv * 8 + i) * 64 + lane;          // granule 0..2047
      int row = f >> 5, slot = f & 31;
      gload16(cb_bf + (size_t)row * 256 + ((slot ^ (row & 7)) * 8),
              &sbuf[(size_t)(wv * 512 + i * 64) * 8]);
    }
  }
  asm volatile("s_waitcnt vmcnt(0)" ::: "memory");
  __syncthreads();  // S3: chunk 0 visible

  float amin[4] = {3.4e38f, 3.4e38f, 3.4e38f, 3.4e38f};

  // ---- chunk loop: 16 chunks x 64 codes, double-buffered async staging ----
  for (int lc = 0; lc < NCH; ++lc) {
    const int kbase = lc * CH;
    unsigned short* cur = &sbuf[(lc & 1) * BUFW];
    unsigned short* nxt = &sbuf[((lc + 1) & 1) * BUFW];
    if (lc < NCH - 1) {  // issue next chunk's DMA before compute
      const unsigned short* base = cb_bf + (size_t)(kbase + CH) * 256;
      #pragma unroll
      for (int i = 0; i < 8; ++i) {
        int f = (wv * 8 + i) * 64 + lane;
        int row = f >> 5, slot = f & 31;
        gload16(base + (size_t)row * 256 + ((slot ^ (row & 7)) * 8),
                nxt + (size_t)(wv * 512 + i * 64) * 8);
      }
    }

    f32x4 acc[4];
    #pragma unroll
    for (int ct = 0; ct < 4; ++ct) acc[ct] = (f32x4){0.f, 0.f, 0.f, 0.f};
    __builtin_amdgcn_s_setprio(1);
    #pragma unroll
    for (int kk = 0; kk < 8; ++kk) {
      int gx = quad + kk * 4;
      bf16x8 b0 = *reinterpret_cast<const bf16x8*>(&cur[(l15)      * 256 + ((gx ^ ( l15       & 7)) * 8)]);
      bf16x8 b1 = *reinterpret_cast<const bf16x8*>(&cur[(16 + l15) * 256 + ((gx ^ ((16 + l15) & 7)) * 8)]);
      bf16x8 b2 = *reinterpret_cast<const bf16x8*>(&cur[(32 + l15) * 256 + ((gx ^ ((32 + l15) & 7)) * 8)]);
      bf16x8 b3 = *reinterpret_cast<const bf16x8*>(&cur[(48 + l15) * 256 + ((gx ^ ((48 + l15) & 7)) * 8)]);
      acc[0] = __builtin_amdgcn_mfma_f32_16x16x32_bf16(afrag[kk], b0, acc[0], 0, 0, 0);
      acc[1] = __builtin_amdgcn_mfma_f32_16x16x32_bf16(afrag[kk], b1, acc[1], 0, 0, 0);
      acc[2] = __builtin_amdgcn_mfma_f32_16x16x32_bf16(afrag[kk], b2, acc[2], 0, 0, 0);
      acc[3] = __builtin_amdgcn_mfma_f32_16x16x32_bf16(afrag[kk], b3, acc[3], 0, 0, 0);
    }
    __builtin_amdgcn_s_setprio(0);

    float e0 = ee_lds[kbase + l15],      e1 = ee_lds[kbase + 16 + l15];
    float e2 = ee_lds[kbase + 32 + l15], e3 = ee_lds[kbase + 48 + l15];
    float en0 = sqrtf(e0), en1 = sqrtf(e1), en2 = sqrtf(e2), en3 = sqrtf(e3);
    #pragma unroll
    for (int r = 0; r < 4; ++r) {
      float d0 = e0 - 2.f * acc[0][r];
      float d1 = e1 - 2.f * acc[1][r];
      float d2 = e2 - 2.f * acc[2][r];
      float d3 = e3 - 2.f * acc[3][r];
      float w = fminf(fminf(d0, d1), fminf(d2, d3));
      #pragma unroll
      for (int off = 1; off < 16; off <<= 1) w = fminf(w, __shfl_xor(w, off, 64));
      float am = fminf(amin[r], w);
      amin[r] = am;
      int tok = wv * 16 + quad * 4 + r;
      float zn = znreg[r];
      // margin >= 2*eps(bf16 screen); full-K running amin keeps the bound
      if (d0 <= am + 1.5f + 0.002f * zn * en0) {
        int sl = atomicAdd(&ccnt[tok], 1);
        if (sl < MAXC) cand[tok * MAXC + sl] = (unsigned short)(kbase + l15);
      }
      if (d1 <= am + 1.5f + 0.002f * zn * en1) {
        int sl = atomicAdd(&ccnt[tok], 1);
        if (sl < MAXC) cand[tok * MAXC + sl] = (unsigned short)(kbase + 16 + l15);
      }
      if (d2 <= am + 1.5f + 0.002f * zn * en2) {
        int sl = atomicAdd(&ccnt[tok], 1);
        if (sl < MAXC) cand[tok * MAXC + sl] = (unsigned short)(kbase + 32 + l15);
      }
      if (d3 <= am + 1.5f + 0.002f * zn * en3) {
        int sl = atomicAdd(&ccnt[tok], 1);
        if (sl < MAXC) cand[tok * MAXC + sl] = (unsigned short)(kbase + 48 + l15);
      }
    }
    asm volatile("s_waitcnt vmcnt(0)" ::: "memory");  // next-chunk DMA landed
    __syncthreads();                                  // visible to all waves
  }

  // ---- phase 1: exact fp32 rescore (candidate loop 4-way unrolled) ----
  for (int it = 0; it < 16; ++it) {
    int tok = wv * 16 + it;
    int n = n0 + tok;
    float4 zv = *reinterpret_cast<const float4*>(z + (size_t)n * 256 + lane * 4);
    int cnt = ccnt[tok];
    float bs = 3.4e38f; int bk = 0;
    if (cnt > MAXC) {  // overflow safety net: exact scan of all K, 2-unrolled
      for (int k = 0; k < K; k += 2) {
        float4 ea = *reinterpret_cast<const float4*>(cb + (size_t)k * 256 + lane * 4);
        float4 eb = *reinterpret_cast<const float4*>(cb + (size_t)(k + 1) * 256 + lane * 4);
        float pa = zv.x * ea.x + zv.y * ea.y + zv.z * ea.z + zv.w * ea.w;
        float pb = zv.x * eb.x + zv.y * eb.y + zv.z * eb.z + zv.w * eb.w;
        #pragma unroll
        for (int off = 32; off; off >>= 1) {
          pa += __shfl_xor(pa, off, 64);
          pb += __shfl_xor(pb, off, 64);
        }
        float sa = ee_lds[k] - 2.f * pa;
        float sb = ee_lds[k + 1] - 2.f * pb;
        if (sa < bs) { bs = sa; bk = k; }
        if (sb < bs) { bs = sb; bk = k + 1; }
      }
    } else {
      int c = 0;
      for (; c + 4 <= cnt; c += 4) {
        int k0 = cand[tok * MAXC + c];
        int k1 = cand[tok * MAXC + c + 1];
        int k2 = cand[tok * MAXC + c + 2];
        int k3 = cand[tok * MAXC + c + 3];
        float4 e0 = *reinterpret_cast<const float4*>(cb + (size_t)k0 * 256 + lane * 4);
        float4 e1 = *reinterpret_cast<const float4*>(cb + (size_t)k1 * 256 + lane * 4);
        float4 e2 = *reinterpret_cast<const float4*>(cb + (size_t)k2 * 256 + lane * 4);
        float4 e3 = *reinterpret_cast<const float4*>(cb + (size_t)k3 * 256 + lane * 4);
        float p0 = zv.x * e0.x + zv.y * e0.y + zv.z * e0.z + zv.w * e0.w;
        float p1 = zv.x * e1.x + zv.y * e1.y + zv.z * e1.z + zv.w * e1.w;
        float p2 = zv.x * e2.x + zv.y * e2.y + zv.z * e2.z + zv.w * e2.w;
        float p3 = zv.x * e3.x + zv.y * e3.y + zv.z * e3.z + zv.w * e3.w;
        #pragma unroll
        for (int off = 32; off; off >>= 1) {   // 4 independent reduce chains
          p0 += __shfl_xor(p0, off, 64);
          p1 += __shfl_xor(p1, off, 64);
          p2 += __shfl_xor(p2, off, 64);
          p3 += __shfl_xor(p3, off, 64);
        }
        float s0 = ee_lds[k0] - 2.f * p0;
        float s1 = ee_lds[k1] - 2.f * p1;
        float s2 = ee_lds[k2] - 2.f * p2;
        float s3 = ee_lds[k3] - 2.f * p3;
        if (s0 < bs || (s0 == bs && k0 < bk)) { bs = s0; bk = k0; }
        if (s1 < bs || (s1 == bs && k1 < bk)) { bs = s1; bk = k1; }
        if (s2 < bs || (s2 == bs && k2 < bk)) { bs = s2; bk = k2; }
        if (s3 < bs || (s3 == bs && k3 < bk)) { bs = s3; bk = k3; }
      }
      for (; c < cnt; ++c) {
        int k = cand[tok * MAXC + c];
        float4 ev = *reinterpret_cast<const float4*>(cb + (size_t)k * 256 + lane * 4);
        float dp = zv.x * ev.x + zv.y * ev.y + zv.z * ev.z + zv.w * ev.w;
        #pragma unroll
        for (int off = 32; off; off >>= 1) dp += __shfl_xor(dp, off, 64);
        float s = ee_lds[k] - 2.f * dp;   // identical on all lanes
        if (s < bs || (s == bs && k < bk)) { bs = s; bk = k; }
      }
    }
    bkbuf[tok] = (unsigned short)bk;
  }

  // ---- phase 2: outputs + loss, 2 tokens in flight ----
  float lsum = 0.f, msum = 0.f;
  for (int it = 0; it < 16; it += 2) {
    int tokA = wv * 16 + it, tokB = tokA + 1;
    int na = n0 + tokA, nb = n0 + tokB;
    int ba = bkbuf[tokA], bb = bkbuf[tokB];
    float4 za = *reinterpret_cast<const float4*>(z + (size_t)na * 256 + lane * 4);
    float4 zb = *reinterpret_cast<const float4*>(z + (size_t)nb * 256 + lane * 4);
    float4 qa = *reinterpret_cast<const float4*>(cb + (size_t)ba * 256 + lane * 4);
    float4 qb = *reinterpret_cast<const float4*>(cb + (size_t)bb * 256 + lane * 4);
    float ma = mask[na], mb = mask[nb];
    float4 oa; oa.x = qa.x * ma; oa.y = qa.y * ma; oa.z = qa.z * ma; oa.w = qa.w * ma;
    float4 ob; ob.x = qb.x * mb; ob.y = qb.y * mb; ob.z = qb.z * mb; ob.w = qb.w * mb;
    *reinterpret_cast<float4*>(out_q + (size_t)na * 256 + lane * 4) = oa;
    *reinterpret_cast<float4*>(out_q + (size_t)nb * 256 + lane * 4) = ob;
    float dxa = za.x - qa.x, dya = za.y - qa.y, dza = za.z - qa.z, dwa = za.w - qa.w;
    float dxb = zb.x - qb.x, dyb = zb.y - qb.y, dzb = zb.z - qb.z, dwb = zb.w - qb.w;
    lsum = fmaf(ma, dxa * dxa + dya * dya + dza * dza + dwa * dwa, lsum);
    lsum = fmaf(mb, dxb * dxb + dyb * dyb + dzb * dzb + dwb * dwb, lsum);
    if (lane == 0) {
      msum += ma + mb;
      out_idx_f[na] = (ma > 0.f) ? (float)ba : 0.f;
      out_idx_f[nb] = (mb > 0.f) ? (float)bb : 0.f;
    }
  }
  #pragma unroll
  for (int off = 32; off; off >>= 1) lsum += __shfl_down(lsum, off, 64);
  if (lane == 0) { red[wv] = lsum; red[4 + wv] = msum; }
  __syncthreads();
  if (t == 0) {
    atomicAdd(&acc2[0], red[0] + red[1] + red[2] + red[3]);
    atomicAdd(&acc2[1], red[4] + red[5] + red[6] + red[7]);
    __threadfence();
    int prev = atomicAdd(done_ctr, 1);
    last = (prev == nblocks - 1);
  }
  __syncthreads();
  if (last && t == 0) {
    float s  = atomicAdd(&acc2[0], 0.0f);
    float nv = atomicAdd(&acc2[1], 0.0f);
    out_loss[0] = (nv > 0.f) ? (0.25f * s / (nv * 256.0f)) : 0.0f;
  }
}

// ---------------------------------------------------------------------------
extern "C" void kernel_launch(void* const* d_in, const int* in_sizes, int n_in,
                              void* d_out, int out_size, void* d_ws, size_t ws_size,
                              hipStream_t stream) {
  const float* z    = (const float*)d_in[0];  // (N, 256)
  const float* mask = (const float*)d_in[1];  // (N,)
  const float* cb   = (const float*)d_in[2];  // (K, 256)
  const int N = in_sizes[1];                  // 32768
  const int D = 256;
  const int K = in_sizes[2] / D;              // 1024

  float* wsf  = (float*)d_ws;
  float* acc2 = wsf;                          // 2 floats
  int*   dctr = (int*)(wsf + 2);              // 1 int
  float* ee   = wsf + 8;                      // K floats
  unsigned short* cb_bf = (unsigned short*)(ee + K);  // K*256 bf16

  float* out_q     = (float*)d_out;           // N*D
  float* out_loss  = out_q + (size_t)N * D;   // 1
  float* out_idx_f = out_loss + 1;            // N

  vq_prep<<<(K + 3) / 4, 256, 0, stream>>>(cb, cb_bf, ee, acc2, dctr, K);
  vq_main<<<N / TOK, 256, 0, stream>>>(z, cb, cb_bf, ee, mask, out_q,
                                       out_idx_f, out_loss, acc2, dctr, N / TOK, K);
}